// Round 5
// baseline (282.035 us; speedup 1.0000x reference)
//
#include <hip/hip_runtime.h>

static constexpr int G = 128;
static constexpr size_t NVOX = (size_t)G * G * G;               // 2,097,152
static constexpr size_t ENTRIES_PER_PAR = (size_t)64 * 64 * 64; // 262144 (xb,yb,zb)
static constexpr size_t NENTRIES = 8 * ENTRIES_PER_PAR;         // 2,097,152
static constexpr size_t P_BYTES = NENTRIES * 64;                // 128 MiB
static constexpr size_t C_BYTES = NVOX * 8;                     // 16 MiB
static constexpr size_t WS_TWOSTAGE = P_BYTES + C_BYTES;        // 144 MiB
static constexpr size_t WS_DIRECT   = P_BYTES;

// Record 8 B (uint2):
//   x = code16(delta) | q0<<16 | q1<<24      delta = |d1| - |d0|
//   y = q2 | q3<<8 | q4<<16 | q5<<24
// code16: round((delta + 8) * 65535/16) clamped; 0/65535 = saturated (guard).

__device__ __forceinline__ uint32_t quant8(float v) {
    float c = fminf(fmaxf(v, -4.0f), 4.0f);
    return (uint32_t)((c + 4.0f) * 31.875f + 0.5f);
}

__device__ __forceinline__ uint2 make_rec8(const float2* __restrict__ dens,
                                           const float* __restrict__ feat,
                                           int vox) {
    float2 d = dens[vox];
    float delta = fabsf(d.y) - fabsf(d.x);
    int code = (int)((delta + 8.0f) * 4095.9375f + 0.5f);
    code = code < 0 ? 0 : (code > 65535 ? 65535 : code);
    const float2* fp = (const float2*)(feat + (size_t)vox * 6);
    float2 a = fp[0], b = fp[1], c = fp[2];
    uint2 r;
    r.x = (uint32_t)code | (quant8(a.x) << 16) | (quant8(a.y) << 24);
    r.y = quant8(b.x) | (quant8(b.y) << 8) | (quant8(c.x) << 16) | (quant8(c.y) << 24);
    return r;
}

// Stage 1: voxel -> compact 8 B record (streaming, 64 MB read / 16 MiB write).
__global__ __launch_bounds__(256) void compress_voxels(const float2* __restrict__ dens,
                                                       const float* __restrict__ feat,
                                                       uint2* __restrict__ C) {
    size_t v = (size_t)blockIdx.x * blockDim.x + threadIdx.x;
    if (v >= NVOX) return;
    C[v] = make_rec8(dens, feat, (int)v);
}

// Stage 2 v2: one thread per 2x2x2 block (xb,yb,zb) builds ALL 8 parity entries
// from the 3x3x3 record neighborhood: 27 L2-resident loads, 512 B coalesced writes.
__global__ __launch_bounds__(256) void build_blocks_v2(const uint2* __restrict__ C,
                                                       uint4* __restrict__ P4) {
    size_t t = (size_t)blockIdx.x * blockDim.x + threadIdx.x;
    if (t >= ENTRIES_PER_PAR) return;
    int xb = (int)(t >> 12), yb = (int)((t >> 6) & 63), zb = (int)(t & 63);

    int xs[3], ys[3], zs[3];
    #pragma unroll
    for (int d = 0; d < 3; ++d) {
        int x = 2 * xb + d; xs[d] = x < G ? x : G - 1;
        int y = 2 * yb + d; ys[d] = y < G ? y : G - 1;
        int z = 2 * zb + d; zs[d] = z < G ? z : G - 1;
    }

    uint2 r[3][3][3];
    #pragma unroll
    for (int dx = 0; dx < 3; ++dx)
        #pragma unroll
        for (int dy = 0; dy < 3; ++dy) {
            const uint2* row = C + (size_t)(xs[dx] * G + ys[dy]) * G;
            #pragma unroll
            for (int dz = 0; dz < 3; ++dz)
                r[dx][dy][dz] = row[zs[dz]];
        }

    size_t e4 = t * 4;
    #pragma unroll
    for (int p = 0; p < 8; ++p) {
        int px = (p >> 2) & 1, py = (p >> 1) & 1, pz = p & 1;
        uint4* dst = P4 + ((size_t)p << 20) + e4;   // p * ENTRIES_PER_PAR*4
        // slot s = (sx<<2)|(sy<<1)|sz ; two slots per uint4
        uint2 s0 = r[px + 0][py + 0][pz + 0], s1 = r[px + 0][py + 0][pz + 1];
        uint2 s2 = r[px + 0][py + 1][pz + 0], s3 = r[px + 0][py + 1][pz + 1];
        uint2 s4 = r[px + 1][py + 0][pz + 0], s5 = r[px + 1][py + 0][pz + 1];
        uint2 s6 = r[px + 1][py + 1][pz + 0], s7 = r[px + 1][py + 1][pz + 1];
        dst[0] = make_uint4(s0.x, s0.y, s1.x, s1.y);
        dst[1] = make_uint4(s2.x, s2.y, s3.x, s3.y);
        dst[2] = make_uint4(s4.x, s4.y, s5.x, s5.y);
        dst[3] = make_uint4(s6.x, s6.y, s7.x, s7.y);
    }
}

// Fallback stage 2 straight from raw inputs (if ws too small for compact array).
__global__ __launch_bounds__(256) void build_blocks_direct(const float2* __restrict__ dens,
                                                           const float* __restrict__ feat,
                                                           uint4* __restrict__ P4) {
    size_t t = (size_t)blockIdx.x * blockDim.x + threadIdx.x;
    if (t >= NENTRIES) return;
    int p = (int)(t >> 18);
    int e = (int)(t & (ENTRIES_PER_PAR - 1));
    int xb = e >> 12, yb = (e >> 6) & 63, zb = e & 63;
    int x0 = 2 * xb + ((p >> 2) & 1);
    int y0 = 2 * yb + ((p >> 1) & 1);
    int z0 = 2 * zb + (p & 1);
    uint2 r[8];
    #pragma unroll
    for (int s = 0; s < 8; ++s) {
        int x = x0 + ((s >> 2) & 1); x = x < G ? x : G - 1;
        int y = y0 + ((s >> 1) & 1); y = y < G ? y : G - 1;
        int z = z0 + (s & 1);        z = z < G ? z : G - 1;
        r[s] = make_rec8(dens, feat, (x * G + y) * G + z);
    }
    size_t o = t * 4;
    P4[o + 0] = make_uint4(r[0].x, r[0].y, r[1].x, r[1].y);
    P4[o + 1] = make_uint4(r[2].x, r[2].y, r[3].x, r[3].y);
    P4[o + 2] = make_uint4(r[4].x, r[4].y, r[5].x, r[5].y);
    P4[o + 3] = make_uint4(r[6].x, r[6].y, r[7].x, r[7].y);
}

struct PtWork {
    int ix, iy, iz;
    float w[8];
    const uint4* L;
};

__device__ __forceinline__ void pt_setup(float px_, float py_, float pz_,
                                         const uint4* __restrict__ P4, PtWork& W) {
    // Mirror reference fp32 op order: pos = ((p/64 + 1) * 128 - 1) * 0.5
    float posx = ((px_ / 64.0f + 1.0f) * 128.0f - 1.0f) * 0.5f;
    float posy = ((py_ / 64.0f + 1.0f) * 128.0f - 1.0f) * 0.5f;
    float posz = ((pz_ / 64.0f + 1.0f) * 128.0f - 1.0f) * 0.5f;
    float bx = floorf(posx), by = floorf(posy), bz = floorf(posz);
    W.ix = (int)bx; W.iy = (int)by; W.iz = (int)bz;
    float fx = posx - bx, fy = posy - by, fz = posz - bz;
    float wx0 = 1.0f - fx, wx1 = fx;
    float wy0 = 1.0f - fy, wy1 = fy;
    float wz0 = 1.0f - fz, wz1 = fz;
    W.w[0] = (wx0 * wy0) * wz0; W.w[1] = (wx0 * wy0) * wz1;
    W.w[2] = (wx0 * wy1) * wz0; W.w[3] = (wx0 * wy1) * wz1;
    W.w[4] = (wx1 * wy0) * wz0; W.w[5] = (wx1 * wy0) * wz1;
    W.w[6] = (wx1 * wy1) * wz0; W.w[7] = (wx1 * wy1) * wz1;
    int p = ((W.ix & 1) << 2) | ((W.iy & 1) << 1) | (W.iz & 1);
    int e = ((W.ix >> 1) << 12) | ((W.iy >> 1) << 6) | (W.iz >> 1);
    W.L = P4 + (((size_t)p << 18) + (size_t)e) * 4;
}

__device__ __forceinline__ float4 pt_finish(const PtWork& W,
                                            uint4 L0, uint4 L1, uint4 L2, uint4 L3,
                                            const float2* __restrict__ dens,
                                            const float* __restrict__ palette) {
    float S = 0.0f;
    float F0 = 0.f, F1 = 0.f, F2 = 0.f, F3 = 0.f, F4 = 0.f, F5 = 0.f;
    bool suspect = false;
    uint32_t wl[8] = {L0.x, L0.z, L1.x, L1.z, L2.x, L2.z, L3.x, L3.z};
    uint32_t wh[8] = {L0.y, L0.w, L1.y, L1.w, L2.y, L2.w, L3.y, L3.w};
    #pragma unroll
    for (int s = 0; s < 8; ++s) {
        uint32_t lo = wl[s], hi = wh[s];
        uint32_t code = lo & 0xffffu;
        suspect = suspect || (code == 0u) || (code == 65535u);
        float dl = (float)code * (16.0f / 65535.0f) - 8.0f;
        float ws = W.w[s];
        S  += dl * ws;
        F0 += (float)((lo >> 16) & 255u) * ws;
        F1 += (float)(lo >> 24) * ws;
        F2 += (float)(hi & 255u) * ws;
        F3 += (float)((hi >> 8) & 255u) * ws;
        F4 += (float)((hi >> 16) & 255u) * ws;
        F5 += (float)(hi >> 24) * ws;
    }
    float density;
    if (!suspect && fabsf(S) > 4e-4f) {
        density = (S > 0.0f) ? 1000.0f : 0.0f;
    } else {
        double D0 = 0.0, D1 = 0.0;
        #pragma unroll
        for (int s = 0; s < 8; ++s) {
            int idx = ((W.ix + ((s >> 2) & 1)) * G + (W.iy + ((s >> 1) & 1))) * G + (W.iz + (s & 1));
            float2 dv = dens[idx];
            D0 += fabs((double)dv.x) * (double)W.w[s];
            D1 += fabs((double)dv.y) * (double)W.w[s];
        }
        density = (D1 > D0) ? 1000.0f : 0.0f;
    }
    int k = 0;
    float m = F0;
    if (F1 > m) { m = F1; k = 1; }
    if (F2 > m) { m = F2; k = 2; }
    if (F3 > m) { m = F3; k = 3; }
    if (F4 > m) { m = F4; k = 4; }
    if (F5 > m) { m = F5; k = 5; }
    return make_float4(density, palette[3 * k], palette[3 * k + 1], palette[3 * k + 2]);
}

// 2 points per thread: 8 outstanding uint4 gathers before any consume.
__global__ __launch_bounds__(256) void voxel_main2(
    const float* __restrict__ points,
    const uint4* __restrict__ P4,
    const float2* __restrict__ dens,
    const float* __restrict__ palette,
    float4* __restrict__ out, int n)
{
#pragma clang fp contract(off)
    int t = blockIdx.x * blockDim.x + threadIdx.x;
    int i0 = 2 * t;
    if (i0 >= n) return;
    bool two = (i0 + 1) < n;

    const float2* pp = (const float2*)points;   // points is 8 B-aligned
    float2 a = pp[3 * t + 0];
    float2 b = pp[3 * t + 1];
    float2 c = two ? pp[3 * t + 2] : make_float2(0.f, 0.f);

    PtWork W0, W1;
    pt_setup(a.x, a.y, b.x, P4, W0);
    pt_setup(b.y, c.x, c.y, P4, W1);
    if (!two) W1.L = W0.L;   // harmless dup to keep loads unconditional

    // Issue all 8 gathers up-front.
    uint4 A0 = W0.L[0], A1 = W0.L[1], A2 = W0.L[2], A3 = W0.L[3];
    uint4 B0 = W1.L[0], B1 = W1.L[1], B2 = W1.L[2], B3 = W1.L[3];

    out[i0] = pt_finish(W0, A0, A1, A2, A3, dens, palette);
    if (two) out[i0 + 1] = pt_finish(W1, B0, B1, B2, B3, dens, palette);
}

// Ultimate fallback: direct kernel (no workspace).
__global__ __launch_bounds__(256) void voxel_art_direct(
    const float* __restrict__ points,
    const float2* __restrict__ dens,
    const float* __restrict__ feat,
    const float* __restrict__ palette,
    float4* __restrict__ out, int n)
{
#pragma clang fp contract(off)
    int i = blockIdx.x * blockDim.x + threadIdx.x;
    if (i >= n) return;
    float px = points[3 * i], py = points[3 * i + 1], pz = points[3 * i + 2];
    float posx = ((px / 64.0f + 1.0f) * 128.0f - 1.0f) * 0.5f;
    float posy = ((py / 64.0f + 1.0f) * 128.0f - 1.0f) * 0.5f;
    float posz = ((pz / 64.0f + 1.0f) * 128.0f - 1.0f) * 0.5f;
    float bx = floorf(posx), by = floorf(posy), bz = floorf(posz);
    int ix = (int)bx, iy = (int)by, iz = (int)bz;
    float fx = posx - bx, fy = posy - by, fz = posz - bz;
    int basei = (ix * G + iy) * G + iz;
    float wx[2] = {1.0f - fx, fx}, wy[2] = {1.0f - fy, fy}, wz[2] = {1.0f - fz, fz};
    double d0 = 0.0, d1 = 0.0;
    float f0 = 0, f1 = 0, f2 = 0, f3 = 0, f4 = 0, f5 = 0;
    #pragma unroll
    for (int dx = 0; dx < 2; ++dx)
    #pragma unroll
    for (int dy = 0; dy < 2; ++dy)
    #pragma unroll
    for (int dz = 0; dz < 2; ++dz) {
        int idx = basei + dx * (G * G) + dy * G + dz;
        float wq = (wx[dx] * wy[dy]) * wz[dz];
        float2 dv = dens[idx];
        d0 += fabs((double)dv.x) * (double)wq;
        d1 += fabs((double)dv.y) * (double)wq;
        const float2* fp2 = (const float2*)(feat + (size_t)idx * 6);
        float2 aa = fp2[0], bb = fp2[1], cc = fp2[2];
        f0 += aa.x * wq; f1 += aa.y * wq; f2 += bb.x * wq;
        f3 += bb.y * wq; f4 += cc.x * wq; f5 += cc.y * wq;
    }
    float density = (d1 > d0) ? 1000.0f : 0.0f;
    int k = 0; float m = f0;
    if (f1 > m) { m = f1; k = 1; }
    if (f2 > m) { m = f2; k = 2; }
    if (f3 > m) { m = f3; k = 3; }
    if (f4 > m) { m = f4; k = 4; }
    if (f5 > m) { m = f5; k = 5; }
    out[i] = make_float4(density, palette[3 * k], palette[3 * k + 1], palette[3 * k + 2]);
}

extern "C" void kernel_launch(void* const* d_in, const int* in_sizes, int n_in,
                              void* d_out, int out_size, void* d_ws, size_t ws_size,
                              hipStream_t stream) {
    const float*  points  = (const float*)d_in[0];
    const float2* dens    = (const float2*)d_in[1];
    const float*  feat    = (const float*)d_in[2];
    const float*  palette = (const float*)d_in[3];
    float4*       out     = (float4*)d_out;

    int n = in_sizes[0] / 3;  // 4194304
    int threads = 256;

    if (ws_size >= WS_TWOSTAGE) {
        uint4* P4 = (uint4*)d_ws;
        uint2* C  = (uint2*)((char*)d_ws + P_BYTES);
        compress_voxels<<<(int)((NVOX + 255) / 256), 256, 0, stream>>>(dens, feat, C);
        build_blocks_v2<<<(int)((ENTRIES_PER_PAR + 255) / 256), 256, 0, stream>>>(C, P4);
        int nt = (n + 1) / 2;
        voxel_main2<<<(nt + threads - 1) / threads, threads, 0, stream>>>(points, P4, dens, palette, out, n);
    } else if (ws_size >= WS_DIRECT) {
        uint4* P4 = (uint4*)d_ws;
        build_blocks_direct<<<(int)((NENTRIES + 255) / 256), 256, 0, stream>>>(dens, feat, P4);
        int nt = (n + 1) / 2;
        voxel_main2<<<(nt + threads - 1) / threads, threads, 0, stream>>>(points, P4, dens, palette, out, n);
    } else {
        voxel_art_direct<<<(n + threads - 1) / threads, threads, 0, stream>>>(points, dens, feat, palette, out, n);
    }
}